// Round 1
// baseline (755.540 us; speedup 1.0000x reference)
//
#include <hip/hip_runtime.h>

// ---------------------------------------------------------------------------
// MXFP4 two-layer quant model: y = (x @ dq(W1)^T + b1) @ dq(W2)^T + b2
// T=8192, D=4096, GROUP=32.
// GEMMs ported to the 256x256 8-phase template (T1+T2+T3/T4+T5):
//   BK=64, 8 waves (2Mx4N), 128KB LDS (4 halftile slots/matrix, 16KB each),
//   counted vmcnt(6) (never 0 in main loop), st_16x32-style XOR swizzle
//   (pre-swizzled global source + swizzled ds_read), setprio around MFMA.
// Workspace: Xb(64MB) | Hb(64MB) | Wd(32MB) = 160MB.
// ---------------------------------------------------------------------------

typedef __bf16 bf16;
typedef bf16 bf16x8 __attribute__((ext_vector_type(8)));
typedef float f32x4 __attribute__((ext_vector_type(4)));
typedef int intx4 __attribute__((ext_vector_type(4)));

#define T_DIM 8192
#define D_DIM 4096

__device__ __forceinline__ void gld_lds16(const void* g, void* l) {
    __builtin_amdgcn_global_load_lds(
        (const __attribute__((address_space(1))) void*)g,
        (__attribute__((address_space(3))) void*)l,
        16, 0, 0);
}

// ---- dequant W: codes[D,D] int32 in [0,16), scales[D,D/32] -> bf16 [D,D] ----
__global__ __launch_bounds__(256) void dequant_kernel(
    const int* __restrict__ codes, const float* __restrict__ scales,
    bf16* __restrict__ out)
{
    const size_t tid = (size_t)blockIdx.x * 256 + threadIdx.x;
    const size_t e = tid * 8;                 // 8 elements per thread, same group
    const int row = (int)(e >> 12);           // / 4096
    const int col = (int)(e & 4095);
    const float s = scales[(size_t)row * (D_DIM / 32) + (col >> 5)];
    const intx4 c0 = *(const intx4*)(codes + e);
    const intx4 c1 = *(const intx4*)(codes + e + 4);
    bf16x8 o;
#pragma unroll
    for (int i = 0; i < 8; ++i) {
        const int c = (i < 4) ? c0[i] : c1[i - 4];
        // E2M1 magnitudes x2 packed in nibbles: {0,1,2,3,4,6,8,12}
        float v = (float)((0xC8643210u >> ((c & 7) * 4)) & 0xF) * 0.5f;
        v = (c & 8) ? -v : v;
        o[i] = (bf16)(v * s);
    }
    *(bf16x8*)(out + e) = o;
}

// ---- fp32 -> bf16 ----
__global__ __launch_bounds__(256) void f32_to_bf16_kernel(
    const float* __restrict__ in, bf16* __restrict__ out)
{
    const size_t tid = (size_t)blockIdx.x * 256 + threadIdx.x;
    const size_t e = tid * 8;
    const float4 a = *(const float4*)(in + e);
    const float4 b = *(const float4*)(in + e + 4);
    bf16x8 o;
    o[0] = (bf16)a.x; o[1] = (bf16)a.y; o[2] = (bf16)a.z; o[3] = (bf16)a.w;
    o[4] = (bf16)b.x; o[5] = (bf16)b.y; o[6] = (bf16)b.z; o[7] = (bf16)b.w;
    *(bf16x8*)(out + e) = o;
}

// ---- swizzled LDS fragment read (qbs precomputed per thread) ----
__device__ __forceinline__ bf16x8 fragr(const char* slot, int row, int qbs) {
    return *(const bf16x8*)(slot + row * 64 + qbs);
}

// ---- GEMM: C[M,N] = A[M,K] @ B[N,K]^T + bias; 256x256 tile, BK=64, 8-phase ---
template <bool OUT_BF16>
__global__ __launch_bounds__(512, 2) void gemm_bt_8ph(
    const bf16* __restrict__ A, const bf16* __restrict__ B,
    const float* __restrict__ bias, void* __restrict__ Cout,
    int M, int N, int K)
{
    // A slots: 4 x 16KB at 0..64KB; B slots: 4 x 16KB at 64..128KB.
    // Slot geometry: 256 rows x 32 kcols bf16 (row stride 64B), linear +
    // XOR-swizzle: byte ^= ((row>>3)&1)<<5  (involution, applied on BOTH the
    // staging SOURCE address and the ds_read address; LDS dest stays linear).
    __shared__ alignas(128) char lds[131072];
    char* ldsA = lds;
    char* ldsB = lds + 65536;

    const int u = threadIdx.x;
    const int lane = u & 63;
    const int wave = u >> 6;
    const int wm = wave >> 2;        // 2 M-halves of 128 rows
    const int wn = wave & 3;         // 4 N-quarters of 64 cols
    const int fr = lane & 15;
    // swizzle bit depends only on fr&8 (row = base16k + fr, base multiple of 16)
    const int qbs = ((lane >> 4) * 16) ^ (((fr >> 3) & 1) << 5);

    // T1: XCD-aware bijective swizzle (nwg = 512, divisible by 8)
    const int nwg = gridDim.x * gridDim.y;
    const int bid0 = blockIdx.y * gridDim.x + blockIdx.x;
    const int cpx = nwg >> 3;
    const int sbid = (bid0 & 7) * cpx + (bid0 >> 3);
    const int m0 = (sbid / gridDim.x) * 256;
    const int n0 = (sbid % gridDim.x) * 256;

    // staging: halftile = 128 rows x 32 kcols x 2B = 16KB = 512thr x 2 x 16B.
    // thread u covers LDS linear offsets u*16 (rows 0..127) and 8192+u*16
    // (rows 128..255); source col pre-swizzled so a linear LDS write lands
    // the swizzled layout.
    const int r0 = u >> 2;
    const int cb = ((u & 3) * 16) ^ (((r0 >> 3) & 1) << 5);
    const bf16* pa = A + (size_t)(m0 + r0) * K + (cb >> 1);
    const bf16* pb = B + (size_t)(n0 + r0) * K + (cb >> 1);
    const size_t rstep = (size_t)128 * K;

#define STAGE_A(SLOT, KB) do {                                                 \
    gld_lds16(pa + (KB),         ldsA + (SLOT) * 16384 + u * 16);              \
    gld_lds16(pa + rstep + (KB), ldsA + (SLOT) * 16384 + 8192 + u * 16);       \
  } while (0)
#define STAGE_B(SLOT, KB) do {                                                 \
    gld_lds16(pb + (KB),         ldsB + (SLOT) * 16384 + u * 16);              \
    gld_lds16(pb + rstep + (KB), ldsB + (SLOT) * 16384 + 8192 + u * 16);       \
  } while (0)
#define AS(s) (ldsA + (s) * 16384)
#define BS(s) (ldsB + (s) * 16384)

    const int arow0 = wm * 128 + fr;
    const int brow0 = wn * 64 + fr;

    f32x4 acc[8][4] = {};
    bf16x8 aq[4], bq[4];

// One phase: ds-reads -> stage one halftile -> barrier -> lgkmcnt(0) ->
// setprio(1) -> 16 MFMA -> setprio(0) -> [vmcnt(6)] -> barrier.
// Raw s_barrier (NOT __syncthreads) so the compiler does not drain vmcnt.
#define PHASE(ASLOT, BSLOT, MH, READB, STAGE_STMT, DO_VM)                      \
  do {                                                                         \
    if (READB) {                                                               \
      bq[0] = fragr(BSLOT, brow0,      qbs);                                   \
      bq[1] = fragr(BSLOT, brow0 + 16, qbs);                                   \
      bq[2] = fragr(BSLOT, brow0 + 32, qbs);                                   \
      bq[3] = fragr(BSLOT, brow0 + 48, qbs);                                   \
    }                                                                          \
    aq[0] = fragr(ASLOT, arow0 + (MH) * 64,      qbs);                         \
    aq[1] = fragr(ASLOT, arow0 + (MH) * 64 + 16, qbs);                         \
    aq[2] = fragr(ASLOT, arow0 + (MH) * 64 + 32, qbs);                         \
    aq[3] = fragr(ASLOT, arow0 + (MH) * 64 + 48, qbs);                         \
    STAGE_STMT;                                                                \
    __builtin_amdgcn_s_barrier();                                              \
    asm volatile("s_waitcnt lgkmcnt(0)" ::: "memory");                         \
    __builtin_amdgcn_sched_barrier(0);                                         \
    __builtin_amdgcn_s_setprio(1);                                             \
    _Pragma("unroll")                                                          \
    for (int jj = 0; jj < 4; ++jj) {                                           \
      _Pragma("unroll")                                                        \
      for (int ii = 0; ii < 4; ++ii)                                           \
        acc[(MH) * 4 + ii][jj] = __builtin_amdgcn_mfma_f32_16x16x32_bf16(      \
            aq[ii], bq[jj], acc[(MH) * 4 + ii][jj], 0, 0, 0);                  \
    }                                                                          \
    __builtin_amdgcn_s_setprio(0);                                             \
    if (DO_VM) { asm volatile("s_waitcnt vmcnt(6)" ::: "memory"); }            \
    __builtin_amdgcn_s_barrier();                                              \
  } while (0)

    // Prologue: stage A(0,0) B(0,0) A(0,1) B(0,1) A(1,0) B(1,0) B(1,1)
    // (A(1,1) comes from P0 of iter 0). 14 loads; vmcnt(6) lands the first
    // 8 = exactly the 4 halves phases 0-3 consume.
    STAGE_A(0, 0);
    STAGE_B(0, 0);
    STAGE_A(1, 32);
    STAGE_B(1, 32);
    STAGE_A(2, 64);
    STAGE_B(2, 64);
    STAGE_B(3, 96);
    asm volatile("s_waitcnt vmcnt(6)" ::: "memory");
    __builtin_amdgcn_s_barrier();

    const int NT = K >> 6;     // 64 K-tiles of BK=64
    const int NI = NT >> 1;    // 2 K-tiles per iteration

    for (int it = 0; it < NI; ++it) {
        const int t = it * 2;
        // t even => slot(tile,sub) is FIXED: (t,s)->s, (t+1,s)->2+s
        const int k1 = (t + 1) * 64;                               // always valid
        const int k2 = ((t + 2) < NT ? (t + 2) : (NT - 1)) * 64;   // clamped
        const int k3 = ((t + 3) < NT ? (t + 3) : (NT - 1)) * 64;   // clamped
        // Stage stream ledger: each write >=1 phase after the slot's last read;
        // each read guarded by a vmcnt(6) that is >=3 halves (6 loads) newer.
        PHASE(AS(0), BS(0), 0, 1, STAGE_A(3, k1 + 32), 0);  // P0: A(t+1,1)->A3
        PHASE(AS(0), BS(0), 1, 0, STAGE_B(0, k2),      0);  // P1: B(t+2,0)->B0
        PHASE(AS(1), BS(1), 0, 1, STAGE_A(0, k2),      0);  // P2: A(t+2,0)->A0
        PHASE(AS(1), BS(1), 1, 0, STAGE_B(1, k2 + 32), 1);  // P3: B(t+2,1)->B1 +vm
        PHASE(AS(2), BS(2), 0, 1, STAGE_A(1, k2 + 32), 0);  // P4: A(t+2,1)->A1
        PHASE(AS(2), BS(2), 1, 0, STAGE_B(2, k3),      0);  // P5: B(t+3,0)->B2
        PHASE(AS(3), BS(3), 0, 1, STAGE_A(2, k3),      0);  // P6: A(t+3,0)->A2
        PHASE(AS(3), BS(3), 1, 0, STAGE_B(3, k3 + 32), 1);  // P7: B(t+3,1)->B3 +vm
    }

#undef PHASE
#undef STAGE_A
#undef STAGE_B
#undef AS
#undef BS

    // Epilogue: C/D layout col=lane&15, row=(lane>>4)*4+reg (guide-verified).
    const int cn = fr;
    const int q4 = (lane >> 4) * 4;
#pragma unroll
    for (int j = 0; j < 4; ++j) {
        const int gn = n0 + wn * 64 + j * 16 + cn;
        const float bv = bias[gn];
#pragma unroll
        for (int mf = 0; mf < 8; ++mf) {
            const int gm = m0 + wm * 128 + mf * 16 + q4;
#pragma unroll
            for (int r = 0; r < 4; ++r) {
                const float v = acc[mf][j][r] + bv;
                const size_t idx = (size_t)(gm + r) * N + gn;
                if (OUT_BF16) ((bf16*)Cout)[idx] = (bf16)v;
                else          ((float*)Cout)[idx] = v;
            }
        }
    }
    (void)M;
}

extern "C" void kernel_launch(void* const* d_in, const int* in_sizes, int n_in,
                              void* d_out, int out_size, void* d_ws, size_t ws_size,
                              hipStream_t stream)
{
    const float* x         = (const float*)d_in[0];
    const int*   w1_codes  = (const int*)d_in[1];
    const float* w1_scales = (const float*)d_in[2];
    const float* b1        = (const float*)d_in[3];
    const int*   w2_codes  = (const int*)d_in[4];
    const float* w2_scales = (const float*)d_in[5];
    const float* b2        = (const float*)d_in[6];
    float* y = (float*)d_out;

    char* ws = (char*)d_ws;
    bf16* Xb = (bf16*)ws;                                      // 64 MB
    bf16* Hb = (bf16*)(ws + (size_t)T_DIM * D_DIM * 2);        // 64 MB
    bf16* Wd = (bf16*)(ws + (size_t)2 * T_DIM * D_DIM * 2);    // 32 MB (W1/W2)

    // x -> bf16
    f32_to_bf16_kernel<<<(T_DIM * (size_t)D_DIM) / 8 / 256, 256, 0, stream>>>(x, Xb);
    // dequant W1
    dequant_kernel<<<(D_DIM * (size_t)D_DIM) / 8 / 256, 256, 0, stream>>>(w1_codes, w1_scales, Wd);
    // GEMM1: Hb = Xb @ Wd^T + b1 (bf16 out)
    dim3 grid(D_DIM / 256, T_DIM / 256);   // (N/256=16, M/256=32) = 512 blocks
    gemm_bt_8ph<true><<<grid, 512, 0, stream>>>(Xb, Wd, b1, (void*)Hb,
                                                T_DIM, D_DIM, D_DIM);
    // dequant W2 (reuses Wd; stream order serializes vs GEMM1)
    dequant_kernel<<<(D_DIM * (size_t)D_DIM) / 8 / 256, 256, 0, stream>>>(w2_codes, w2_scales, Wd);
    // GEMM2: y = Hb @ Wd^T + b2 (fp32 out)
    gemm_bt_8ph<false><<<grid, 512, 0, stream>>>(Hb, Wd, b2, (void*)y,
                                                 T_DIM, D_DIM, D_DIM);
}